// Round 3
// baseline (6719.172 us; speedup 1.0000x reference)
//
#include <hip/hip_runtime.h>
#include <hip/hip_bf16.h>

// Problem constants
#define B_  64
#define T_  512
#define E_  256
#define H_  512
#define G4_ 2048
#define C_  4

typedef __attribute__((ext_vector_type(4))) float  f32x4;
typedef __attribute__((ext_vector_type(8))) __bf16 bf16x8;
typedef __attribute__((ext_vector_type(8))) short  short8;   // no HIP builtin 'short8'
typedef __attribute__((ext_vector_type(4))) short  s16x4;    // renamed: HIP predefines 'short4'

union V16 { f32x4 f; bf16x8 b; short8 s; };

__device__ __forceinline__ float sigmoid_(float x) { return 1.0f / (1.0f + __expf(-x)); }
__device__ __forceinline__ float tanh_(float x)    { return 1.0f - 2.0f / (__expf(2.0f * x) + 1.0f); }

// Deterministic RNE fp32 -> bf16 (inputs are finite; no NaN handling needed)
__device__ __forceinline__ short f2bf(float f) {
  union { float f; unsigned u; } v; v.f = f;
  return (short)((v.u + 0x7FFFu + ((v.u >> 16) & 1u)) >> 16);
}

// ---------------------------------------------------------------------------
// Phase 1: xg[t][g][b][d] = (emb[x[b][t]] @ W_ih^T)[g*512+d]   (bias added later)
// fp32 inputs; embeddings converted to bf16 into LDS at gather; W_ih rows
// converted to bf16 fragments in the inner loop (W_ih fp32 = 2 MB, L2-resident).
// Grid: 512 blocks (one per t) x 256 threads (4 waves); wave w owns gate rows
// [w*512, w*512+512). M=gates, N=64 batches, K=256.
// ---------------------------------------------------------------------------
__global__ __launch_bounds__(256, 1) void xg_kernel(
    const int* __restrict__ x, const float* __restrict__ emb,
    const float* __restrict__ W_ih,
    __hip_bfloat16* __restrict__ xg)
{
  const int t   = blockIdx.x;
  const int tid = threadIdx.x;
  __shared__ int s_idx[B_];
  __shared__ __hip_bfloat16 s_e[B_][E_ + 8];   // +8 pad: 2-way LDS aliasing only

  if (tid < B_) s_idx[tid] = x[tid * T_ + t];
  __syncthreads();
  {
    // gather 64 embedding rows (256 fp32 each) -> bf16 LDS; thread = (b, 64-elem chunk)
    int b = tid >> 2, ch = tid & 3;
    const float* src = emb + (size_t)s_idx[b] * E_ + ch * 64;
    short* dst = (short*)&s_e[b][ch * 64];
#pragma unroll
    for (int i = 0; i < 16; i++) {
      f32x4 v = *(const f32x4*)(src + i * 4);
      s16x4 s;
      s[0] = f2bf(v[0]); s[1] = f2bf(v[1]); s[2] = f2bf(v[2]); s[3] = f2bf(v[3]);
      *(s16x4*)(dst + i * 4) = s;
    }
  }
  __syncthreads();

  const int wv   = tid >> 6;
  const int lane = tid & 63;
  const int ln15 = lane & 15, quad = lane >> 4;

  // B fragments: B[k][n] with n=lane&15 (batch), k=quad*8 + ks*32 + j
  V16 breg[4][8];
#pragma unroll
  for (int nt = 0; nt < 4; nt++)
#pragma unroll
    for (int ks = 0; ks < 8; ks++)
      breg[nt][ks].f = *(const f32x4*)(&s_e[nt * 16 + ln15][quad * 8 + ks * 32]);

  const int gbase = wv * 512;
  const size_t base_t = (size_t)t * (G4_ * B_);
  for (int mt = 0; mt < 32; mt++) {
    const int grow = gbase + mt * 16 + ln15;
    const float* arow = W_ih + (size_t)grow * E_ + quad * 8;
    V16 areg[8];
#pragma unroll
    for (int ks = 0; ks < 8; ks++) {
      f32x4 lo = *(const f32x4*)(arow + ks * 32);
      f32x4 hi = *(const f32x4*)(arow + ks * 32 + 4);
      short8 s;
      s[0] = f2bf(lo[0]); s[1] = f2bf(lo[1]); s[2] = f2bf(lo[2]); s[3] = f2bf(lo[3]);
      s[4] = f2bf(hi[0]); s[5] = f2bf(hi[1]); s[6] = f2bf(hi[2]); s[7] = f2bf(hi[3]);
      areg[ks].s = s;
    }

    f32x4 acc[4];
#pragma unroll
    for (int nt = 0; nt < 4; nt++) acc[nt] = (f32x4){0.f, 0.f, 0.f, 0.f};
#pragma unroll
    for (int ks = 0; ks < 8; ks++)
#pragma unroll
      for (int nt = 0; nt < 4; nt++)
        acc[nt] = __builtin_amdgcn_mfma_f32_16x16x32_bf16(areg[ks].b, breg[nt][ks].b, acc[nt], 0, 0, 0);

    // C layout: n = lane&15 (batch), m = quad*4 + r (gate row in tile)
    const int mrow0 = gbase + mt * 16 + quad * 4;
#pragma unroll
    for (int nt = 0; nt < 4; nt++) {
      const int batch = nt * 16 + ln15;
#pragma unroll
      for (int r = 0; r < 4; r++) {
        const int grow2 = mrow0 + r;
        const int d = grow2 & 511;               // gate group g == wv
        short sv = f2bf(acc[nt][r]);
        *((short*)xg + base_t + ((size_t)wv << 15) + ((size_t)batch << 9) + d) = sv;
      }
    }
  }
}

// ---------------------------------------------------------------------------
// Phase 2: persistent recurrent kernel. 256 blocks x 128 threads (2 waves).
// Block (pb = blk&3, pd = blk>>2): batches [pb*16,pb*16+16), h-dims [pd*8,pd*8+8)
// -> 32 gate rows. W_hh (fp32) converted once to register-resident bf16
// fragments. Per step: 16 dwordx4 h loads (LLC), 16 MFMAs, LDS shuffle ->
// per-lane fp32 gate math (c in a register), bf16 h write, agent release +
// monotonic flag, poll own batch-group's 64 flags. Block 0 does the fp32 FC.
// ---------------------------------------------------------------------------
__global__ __launch_bounds__(128, 1) void lstm_kernel(
    const float* __restrict__ W_hh,
    const float* __restrict__ b_ih, const float* __restrict__ b_hh,
    const float* __restrict__ W_fc, const float* __restrict__ b_fc,
    const __hip_bfloat16* __restrict__ xg,
    unsigned int* flags, __hip_bfloat16* hbuf /*[2][64][512]*/, float* hT,
    float* out)
{
  const int tid  = threadIdx.x;
  const int blk  = blockIdx.x;
  const int pb   = blk & 3;
  const int pd   = blk >> 2;
  const int d0   = pd * 8;
  const int wv   = tid >> 6;
  const int lane = tid & 63;
  const int ln15 = lane & 15, quad = lane >> 4;

  __shared__ float s_pre[4 * 16 * 8];   // [g][batch][dim]

  // Register-resident A fragments from fp32 W_hh:
  // A[m=lane&15][k = quad*8 + ks*32 + j]; m<8 -> gate grp wv*2, else wv*2+1
  V16 areg[16];
  {
    const int grp = wv * 2 + (ln15 >> 3);
    const int row = grp * 512 + d0 + (ln15 & 7);
    const float* ap = W_hh + (size_t)row * H_ + quad * 8;
#pragma unroll
    for (int ks = 0; ks < 16; ks++) {
      f32x4 lo = *(const f32x4*)(ap + ks * 32);
      f32x4 hi = *(const f32x4*)(ap + ks * 32 + 4);
      short8 s;
      s[0] = f2bf(lo[0]); s[1] = f2bf(lo[1]); s[2] = f2bf(lo[2]); s[3] = f2bf(lo[3]);
      s[4] = f2bf(hi[0]); s[5] = f2bf(hi[1]); s[6] = f2bf(hi[2]); s[7] = f2bf(hi[3]);
      areg[ks].s = s;
    }
  }

  // Nonlinearity lane mapping: dim-fastest so h writes are 16B-contiguous runs
  const int nd = tid & 7, nb = tid >> 3;
  const int gb = pb * 16 + nb;     // global batch
  const int dg = d0 + nd;          // global h-dim
  const float bias_i = b_ih[dg]        + b_hh[dg];
  const float bias_f = b_ih[512 + dg]  + b_hh[512 + dg];
  const float bias_g = b_ih[1024 + dg] + b_hh[1024 + dg];
  const float bias_o = b_ih[1536 + dg] + b_hh[1536 + dg];
  float c = 0.0f;
  const int myflag = pb * 64 + pd;

  for (int t = 0; t < T_; t++) {
    const int cur = t & 1, nxt = cur ^ 1;

    // xg prefetch (consumed after the LDS barrier)
    const size_t xoff = (size_t)t * (G4_ * B_) + ((size_t)gb << 9) + dg;
    const __hip_bfloat16 xgi = xg[xoff];
    const __hip_bfloat16 xgf = xg[xoff + (1u << 15)];
    const __hip_bfloat16 xgg = xg[xoff + (2u << 15)];
    const __hip_bfloat16 xgo = xg[xoff + (3u << 15)];

    // B fragments straight from the broadcast h buffer (LLC)
    const __hip_bfloat16* hb = hbuf + (size_t)cur * (B_ * H_) +
                               (size_t)(pb * 16 + ln15) * H_ + quad * 8;
    V16 breg[16];
#pragma unroll
    for (int ks = 0; ks < 16; ks++)
      breg[ks].f = *(const f32x4*)(hb + ks * 32);

    f32x4 acc0 = (f32x4){0.f, 0.f, 0.f, 0.f};
    f32x4 acc1 = (f32x4){0.f, 0.f, 0.f, 0.f};
#pragma unroll
    for (int ks = 0; ks < 16; ks += 2) {
      acc0 = __builtin_amdgcn_mfma_f32_16x16x32_bf16(areg[ks].b,     breg[ks].b,     acc0, 0, 0, 0);
      acc1 = __builtin_amdgcn_mfma_f32_16x16x32_bf16(areg[ks + 1].b, breg[ks + 1].b, acc1, 0, 0, 0);
    }
    const f32x4 accs = acc0 + acc1;

    // scatter preactivations: C row m = quad*4+r -> (gate grp, dim); col = batch
#pragma unroll
    for (int r = 0; r < 4; r++) {
      const int m = quad * 4 + r;
      const int g = wv * 2 + (m >> 3);
      s_pre[g * 128 + ln15 * 8 + (m & 7)] = accs[r];
    }
    __syncthreads();

    {
      const float pi = s_pre[tid]       + bias_i + __bfloat162float(xgi);
      const float pf = s_pre[128 + tid] + bias_f + __bfloat162float(xgf);
      const float pg = s_pre[256 + tid] + bias_g + __bfloat162float(xgg);
      const float po = s_pre[384 + tid] + bias_o + __bfloat162float(xgo);
      const float i_ = sigmoid_(pi), f_ = sigmoid_(pf);
      const float g_ = tanh_(pg),    o_ = sigmoid_(po);
      c = f_ * c + i_ * g_;
      const float h = o_ * tanh_(c);
      ((short*)hbuf)[(size_t)nxt * (B_ * H_) + (size_t)gb * H_ + dg] = f2bf(h);
      if (t == T_ - 1) hT[gb * H_ + dg] = h;
    }
    __syncthreads();   // drains stores (vmcnt 0) + joins waves before publish

    if (tid == 0) {
      __builtin_amdgcn_fence(__ATOMIC_RELEASE, "agent");   // flush writes to agent scope
      __hip_atomic_store(&flags[myflag], (unsigned)(t + 1),
                         __ATOMIC_RELAXED, __HIP_MEMORY_SCOPE_AGENT);
    }
    // Poll only our batch group's 64 flags (monotonic counters)
    {
      const unsigned tgt = (unsigned)(t + 1);
      const unsigned* fp = flags + pb * 64 + lane;
      while (__hip_atomic_load(fp, __ATOMIC_RELAXED, __HIP_MEMORY_SCOPE_AGENT) < tgt) {}
      __builtin_amdgcn_fence(__ATOMIC_ACQUIRE, "agent");   // invalidate stale caches
    }
  }

  // Phase 3: fp32 FC by block 0 only (needs all 256 blocks' hT slices)
  if (blk == 0) {
    for (int j = tid; j < 256; j += 128)
      while (__hip_atomic_load(&flags[j], __ATOMIC_RELAXED, __HIP_MEMORY_SCOPE_AGENT) < (unsigned)T_) {}
    __builtin_amdgcn_fence(__ATOMIC_ACQUIRE, "agent");
    __syncthreads();
    for (int o = tid; o < B_ * C_; o += 128) {
      const int b = o >> 2, cl = o & 3;
      const f32x4* hr = (const f32x4*)(hT + b * H_);
      const f32x4* wr = (const f32x4*)(W_fc + cl * H_);
      float s = 0.f;
      for (int d4 = 0; d4 < H_ / 4; d4++) {
        const f32x4 hv = hr[d4];
        const f32x4 wv4 = wr[d4];
        s += hv[0] * wv4[0] + hv[1] * wv4[1] + hv[2] * wv4[2] + hv[3] * wv4[3];
      }
      s += b_fc[cl];
      out[o] = s;
    }
  }
}

// ---------------------------------------------------------------------------
// Workspace map:
//   [0, 1024)            : flags[256] (uint32, zeroed every launch)
//   [4096, 135168)       : hbuf[2][64][512] bf16 (both buffers zeroed = h0)
//   [135168, 266240)     : hT[64][512] fp32
//   [524288, 134742016)  : xg[T][4][B][512] bf16 (128 MiB)
// ---------------------------------------------------------------------------
extern "C" void kernel_launch(void* const* d_in, const int* in_sizes, int n_in,
                              void* d_out, int out_size, void* d_ws, size_t ws_size,
                              hipStream_t stream) {
  const int*   x    = (const int*)d_in[0];
  const float* emb  = (const float*)d_in[1];
  const float* W_ih = (const float*)d_in[2];
  const float* W_hh = (const float*)d_in[3];
  const float* b_ih = (const float*)d_in[4];
  const float* b_hh = (const float*)d_in[5];
  const float* W_fc = (const float*)d_in[6];
  const float* b_fc = (const float*)d_in[7];
  float* out = (float*)d_out;

  char* ws = (char*)d_ws;
  const size_t XG_OFF = 524288;
  const size_t NEEDED = XG_OFF + (size_t)T_ * G4_ * B_ * 2;
  if (ws_size < NEEDED) return;  // leaves out zeroed -> stub-like absmax signals ws problem

  unsigned int*   flags = (unsigned int*)ws;
  __hip_bfloat16* hbuf  = (__hip_bfloat16*)(ws + 4096);
  float*          hT    = (float*)(ws + 135168);
  __hip_bfloat16* xg    = (__hip_bfloat16*)(ws + XG_OFF);

  // zero flags + both h buffers (h0 = 0); ws is re-poisoned before every launch
  (void)hipMemsetAsync(ws, 0, 135168, stream);

  xg_kernel<<<T_, 256, 0, stream>>>(x, emb, W_ih, xg);
  lstm_kernel<<<256, 128, 0, stream>>>(W_hh, b_ih, b_hh, W_fc, b_fc, xg,
                                       flags, hbuf, hT, out);
}

// Round 4
// 2353.567 us; speedup vs baseline: 2.8549x; 2.8549x over previous
//
#include <hip/hip_runtime.h>
#include <hip/hip_bf16.h>

// Problem constants
#define B_  64
#define T_  512
#define E_  256
#define H_  512
#define G4_ 2048
#define C_  4

typedef __attribute__((ext_vector_type(4))) float  f32x4;
typedef __attribute__((ext_vector_type(8))) __bf16 bf16x8;
typedef __attribute__((ext_vector_type(8))) short  short8;   // no HIP builtin 'short8'
typedef __attribute__((ext_vector_type(4))) short  s16x4;    // HIP predefines 'short4'

union V16 { f32x4 f; bf16x8 b; short8 s; };

__device__ __forceinline__ float sigmoid_(float x) { return 1.0f / (1.0f + __expf(-x)); }
__device__ __forceinline__ float tanh_(float x)    { return 1.0f - 2.0f / (__expf(2.0f * x) + 1.0f); }

// Deterministic RNE fp32 -> bf16 (inputs are finite; no NaN handling needed)
__device__ __forceinline__ short f2bf(float f) {
  union { float f; unsigned u; } v; v.f = f;
  return (short)((v.u + 0x7FFFu + ((v.u >> 16) & 1u)) >> 16);
}

// --- per-access LLC-coherent ops (sc0 sc1 = bypass L1+L2, hit the coherent
// point). These replace whole-cache fences (buffer_wbl2/buffer_inv) that made
// round-3's per-step sync cost 12.6 us. ---
__device__ __forceinline__ void store_short_llc(void* p, unsigned v) {
  asm volatile("global_store_short %0, %1, off sc0 sc1" :: "v"(p), "v"(v) : "memory");
}
__device__ __forceinline__ void store_dword_llc(void* p, float v) {
  asm volatile("global_store_dword %0, %1, off sc0 sc1" :: "v"(p), "v"(v) : "memory");
}
// 16 pipelined coherent 16B loads from consecutive 64B strides + one drain.
__device__ __forceinline__ void load_h16_llc(const void* p, V16* b) {
  asm volatile(
      "global_load_dwordx4 %0, %16, off sc0 sc1\n\t"
      "global_load_dwordx4 %1, %16, off offset:64 sc0 sc1\n\t"
      "global_load_dwordx4 %2, %16, off offset:128 sc0 sc1\n\t"
      "global_load_dwordx4 %3, %16, off offset:192 sc0 sc1\n\t"
      "global_load_dwordx4 %4, %16, off offset:256 sc0 sc1\n\t"
      "global_load_dwordx4 %5, %16, off offset:320 sc0 sc1\n\t"
      "global_load_dwordx4 %6, %16, off offset:384 sc0 sc1\n\t"
      "global_load_dwordx4 %7, %16, off offset:448 sc0 sc1\n\t"
      "global_load_dwordx4 %8, %16, off offset:512 sc0 sc1\n\t"
      "global_load_dwordx4 %9, %16, off offset:576 sc0 sc1\n\t"
      "global_load_dwordx4 %10, %16, off offset:640 sc0 sc1\n\t"
      "global_load_dwordx4 %11, %16, off offset:704 sc0 sc1\n\t"
      "global_load_dwordx4 %12, %16, off offset:768 sc0 sc1\n\t"
      "global_load_dwordx4 %13, %16, off offset:832 sc0 sc1\n\t"
      "global_load_dwordx4 %14, %16, off offset:896 sc0 sc1\n\t"
      "global_load_dwordx4 %15, %16, off offset:960 sc0 sc1\n\t"
      "s_waitcnt vmcnt(0)"
      : "=&v"(b[0].f), "=&v"(b[1].f), "=&v"(b[2].f), "=&v"(b[3].f),
        "=&v"(b[4].f), "=&v"(b[5].f), "=&v"(b[6].f), "=&v"(b[7].f),
        "=&v"(b[8].f), "=&v"(b[9].f), "=&v"(b[10].f), "=&v"(b[11].f),
        "=&v"(b[12].f), "=&v"(b[13].f), "=&v"(b[14].f), "=&v"(b[15].f)
      : "v"(p)
      : "memory");
}

// ---------------------------------------------------------------------------
// Phase 1: xg[t][g][b][d] = (emb[x[b][t]] @ W_ih^T)[g*512+d]   (bias added later)
// unchanged from round 3 (passed; ~250 us).
// ---------------------------------------------------------------------------
__global__ __launch_bounds__(256, 1) void xg_kernel(
    const int* __restrict__ x, const float* __restrict__ emb,
    const float* __restrict__ W_ih,
    __hip_bfloat16* __restrict__ xg)
{
  const int t   = blockIdx.x;
  const int tid = threadIdx.x;
  __shared__ int s_idx[B_];
  __shared__ __hip_bfloat16 s_e[B_][E_ + 8];

  if (tid < B_) s_idx[tid] = x[tid * T_ + t];
  __syncthreads();
  {
    int b = tid >> 2, ch = tid & 3;
    const float* src = emb + (size_t)s_idx[b] * E_ + ch * 64;
    short* dst = (short*)&s_e[b][ch * 64];
#pragma unroll
    for (int i = 0; i < 16; i++) {
      f32x4 v = *(const f32x4*)(src + i * 4);
      s16x4 s;
      s[0] = f2bf(v[0]); s[1] = f2bf(v[1]); s[2] = f2bf(v[2]); s[3] = f2bf(v[3]);
      *(s16x4*)(dst + i * 4) = s;
    }
  }
  __syncthreads();

  const int wv   = tid >> 6;
  const int lane = tid & 63;
  const int ln15 = lane & 15, quad = lane >> 4;

  V16 breg[4][8];
#pragma unroll
  for (int nt = 0; nt < 4; nt++)
#pragma unroll
    for (int ks = 0; ks < 8; ks++)
      breg[nt][ks].f = *(const f32x4*)(&s_e[nt * 16 + ln15][quad * 8 + ks * 32]);

  const int gbase = wv * 512;
  const size_t base_t = (size_t)t * (G4_ * B_);
  for (int mt = 0; mt < 32; mt++) {
    const int grow = gbase + mt * 16 + ln15;
    const float* arow = W_ih + (size_t)grow * E_ + quad * 8;
    V16 areg[8];
#pragma unroll
    for (int ks = 0; ks < 8; ks++) {
      f32x4 lo = *(const f32x4*)(arow + ks * 32);
      f32x4 hi = *(const f32x4*)(arow + ks * 32 + 4);
      short8 s;
      s[0] = f2bf(lo[0]); s[1] = f2bf(lo[1]); s[2] = f2bf(lo[2]); s[3] = f2bf(lo[3]);
      s[4] = f2bf(hi[0]); s[5] = f2bf(hi[1]); s[6] = f2bf(hi[2]); s[7] = f2bf(hi[3]);
      areg[ks].s = s;
    }

    f32x4 acc[4];
#pragma unroll
    for (int nt = 0; nt < 4; nt++) acc[nt] = (f32x4){0.f, 0.f, 0.f, 0.f};
#pragma unroll
    for (int ks = 0; ks < 8; ks++)
#pragma unroll
      for (int nt = 0; nt < 4; nt++)
        acc[nt] = __builtin_amdgcn_mfma_f32_16x16x32_bf16(areg[ks].b, breg[nt][ks].b, acc[nt], 0, 0, 0);

    const int mrow0 = gbase + mt * 16 + quad * 4;
#pragma unroll
    for (int nt = 0; nt < 4; nt++) {
      const int batch = nt * 16 + ln15;
#pragma unroll
      for (int r = 0; r < 4; r++) {
        const int grow2 = mrow0 + r;
        const int d = grow2 & 511;
        short sv = f2bf(acc[nt][r]);
        *((short*)xg + base_t + ((size_t)wv << 15) + ((size_t)batch << 9) + d) = sv;
      }
    }
  }
}

// ---------------------------------------------------------------------------
// Phase 2: persistent recurrent kernel, 256 blocks x 128 threads.
// Same structure as round 3 but ALL cross-XCD traffic (h, hT) moves through
// per-access sc0sc1 coherent ops; no per-step cache-wide fences. Ordering:
// sc1 stores ack at the LLC, __syncthreads drains vmcnt(0) before the flag
// publish, so flag-after-data holds without buffer_wbl2.
// ---------------------------------------------------------------------------
__global__ __launch_bounds__(128, 1) void lstm_kernel(
    const float* __restrict__ W_hh,
    const float* __restrict__ b_ih, const float* __restrict__ b_hh,
    const float* __restrict__ W_fc, const float* __restrict__ b_fc,
    const __hip_bfloat16* __restrict__ xg,
    unsigned int* flags, __hip_bfloat16* hbuf /*[2][64][512]*/, float* hT,
    float* out)
{
  const int tid  = threadIdx.x;
  const int blk  = blockIdx.x;
  const int pb   = blk & 3;
  const int pd   = blk >> 2;
  const int d0   = pd * 8;
  const int wv   = tid >> 6;
  const int lane = tid & 63;
  const int ln15 = lane & 15, quad = lane >> 4;

  __shared__ float s_pre[4 * 16 * 8];   // [g][batch][dim]

  // Register-resident bf16 A fragments from fp32 W_hh
  V16 areg[16];
  {
    const int grp = wv * 2 + (ln15 >> 3);
    const int row = grp * 512 + d0 + (ln15 & 7);
    const float* ap = W_hh + (size_t)row * H_ + quad * 8;
#pragma unroll
    for (int ks = 0; ks < 16; ks++) {
      f32x4 lo = *(const f32x4*)(ap + ks * 32);
      f32x4 hi = *(const f32x4*)(ap + ks * 32 + 4);
      short8 s;
      s[0] = f2bf(lo[0]); s[1] = f2bf(lo[1]); s[2] = f2bf(lo[2]); s[3] = f2bf(lo[3]);
      s[4] = f2bf(hi[0]); s[5] = f2bf(hi[1]); s[6] = f2bf(hi[2]); s[7] = f2bf(hi[3]);
      areg[ks].s = s;
    }
  }

  const int nd = tid & 7, nb = tid >> 3;
  const int gb = pb * 16 + nb;     // global batch
  const int dg = d0 + nd;          // global h-dim
  const float bias_i = b_ih[dg]        + b_hh[dg];
  const float bias_f = b_ih[512 + dg]  + b_hh[512 + dg];
  const float bias_g = b_ih[1024 + dg] + b_hh[1024 + dg];
  const float bias_o = b_ih[1536 + dg] + b_hh[1536 + dg];
  float c = 0.0f;
  const int myflag = pb * 64 + pd;

  for (int t = 0; t < T_; t++) {
    const int cur = t & 1, nxt = cur ^ 1;

    // xg prefetch (plain cached loads; xg was written before this kernel)
    const size_t xoff = (size_t)t * (G4_ * B_) + ((size_t)gb << 9) + dg;
    const __hip_bfloat16 xgi = xg[xoff];
    const __hip_bfloat16 xgf = xg[xoff + (1u << 15)];
    const __hip_bfloat16 xgg = xg[xoff + (2u << 15)];
    const __hip_bfloat16 xgo = xg[xoff + (3u << 15)];

    // B fragments: coherent pipelined loads straight from the LLC h buffer
    const __hip_bfloat16* hb = hbuf + (size_t)cur * (B_ * H_) +
                               (size_t)(pb * 16 + ln15) * H_ + quad * 8;
    V16 breg[16];
    load_h16_llc(hb, breg);

    f32x4 acc0 = (f32x4){0.f, 0.f, 0.f, 0.f};
    f32x4 acc1 = (f32x4){0.f, 0.f, 0.f, 0.f};
#pragma unroll
    for (int ks = 0; ks < 16; ks += 2) {
      acc0 = __builtin_amdgcn_mfma_f32_16x16x32_bf16(areg[ks].b,     breg[ks].b,     acc0, 0, 0, 0);
      acc1 = __builtin_amdgcn_mfma_f32_16x16x32_bf16(areg[ks + 1].b, breg[ks + 1].b, acc1, 0, 0, 0);
    }
    const f32x4 accs = acc0 + acc1;

#pragma unroll
    for (int r = 0; r < 4; r++) {
      const int m = quad * 4 + r;
      const int g = wv * 2 + (m >> 3);
      s_pre[g * 128 + ln15 * 8 + (m & 7)] = accs[r];
    }
    __syncthreads();

    {
      const float pi = s_pre[tid]       + bias_i + __bfloat162float(xgi);
      const float pf = s_pre[128 + tid] + bias_f + __bfloat162float(xgf);
      const float pg = s_pre[256 + tid] + bias_g + __bfloat162float(xgg);
      const float po = s_pre[384 + tid] + bias_o + __bfloat162float(xgo);
      const float i_ = sigmoid_(pi), f_ = sigmoid_(pf);
      const float g_ = tanh_(pg),    o_ = sigmoid_(po);
      c = f_ * c + i_ * g_;
      const float h = o_ * tanh_(c);
      if (t < T_ - 1) {
        short* hp = (short*)hbuf + (size_t)nxt * (B_ * H_) + (size_t)gb * H_ + dg;
        store_short_llc(hp, (unsigned)(unsigned short)f2bf(h));
      } else {
        store_dword_llc(hT + gb * H_ + dg, h);   // LLC-visible for block 0
      }
    }
    // Drains vmcnt(0) (sc1 stores acked at LLC) + joins waves before publish
    __syncthreads();

    if (tid == 0)
      __hip_atomic_store(&flags[myflag], (unsigned)(t + 1),
                         __ATOMIC_RELAXED, __HIP_MEMORY_SCOPE_AGENT);
    // Poll own batch-group's 64 flags (monotonic; coherent atomic loads)
    {
      const unsigned tgt = (unsigned)(t + 1);
      const unsigned* fp = flags + pb * 64 + lane;
      while (__hip_atomic_load(fp, __ATOMIC_RELAXED, __HIP_MEMORY_SCOPE_AGENT) < tgt) {}
    }
  }

  // Phase 3: fp32 FC by block 0 (hT was written through to LLC; one acquire
  // fence invalidates block-0's own stale lines, then plain loads are fine)
  if (blk == 0) {
    for (int j = tid; j < 256; j += 128)
      while (__hip_atomic_load(&flags[j], __ATOMIC_RELAXED, __HIP_MEMORY_SCOPE_AGENT) < (unsigned)T_) {}
    __builtin_amdgcn_fence(__ATOMIC_ACQUIRE, "agent");
    __syncthreads();
    for (int o = tid; o < B_ * C_; o += 128) {
      const int b = o >> 2, cl = o & 3;
      const f32x4* hr = (const f32x4*)(hT + b * H_);
      const f32x4* wr = (const f32x4*)(W_fc + cl * H_);
      float s = 0.f;
      for (int d4 = 0; d4 < H_ / 4; d4++) {
        const f32x4 hv = hr[d4];
        const f32x4 wv4 = wr[d4];
        s += hv[0] * wv4[0] + hv[1] * wv4[1] + hv[2] * wv4[2] + hv[3] * wv4[3];
      }
      s += b_fc[cl];
      out[o] = s;
    }
  }
}

// ---------------------------------------------------------------------------
// Workspace map:
//   [0, 1024)            : flags[256] (uint32, zeroed every launch)
//   [4096, 135168)       : hbuf[2][64][512] bf16 (both buffers zeroed = h0)
//   [135168, 266240)     : hT[64][512] fp32
//   [524288, 134742016)  : xg[T][4][B][512] bf16 (128 MiB)
// ---------------------------------------------------------------------------
extern "C" void kernel_launch(void* const* d_in, const int* in_sizes, int n_in,
                              void* d_out, int out_size, void* d_ws, size_t ws_size,
                              hipStream_t stream) {
  const int*   x    = (const int*)d_in[0];
  const float* emb  = (const float*)d_in[1];
  const float* W_ih = (const float*)d_in[2];
  const float* W_hh = (const float*)d_in[3];
  const float* b_ih = (const float*)d_in[4];
  const float* b_hh = (const float*)d_in[5];
  const float* W_fc = (const float*)d_in[6];
  const float* b_fc = (const float*)d_in[7];
  float* out = (float*)d_out;

  char* ws = (char*)d_ws;
  const size_t XG_OFF = 524288;
  const size_t NEEDED = XG_OFF + (size_t)T_ * G4_ * B_ * 2;
  if (ws_size < NEEDED) return;

  unsigned int*   flags = (unsigned int*)ws;
  __hip_bfloat16* hbuf  = (__hip_bfloat16*)(ws + 4096);
  float*          hT    = (float*)(ws + 135168);
  __hip_bfloat16* xg    = (__hip_bfloat16*)(ws + XG_OFF);

  (void)hipMemsetAsync(ws, 0, 135168, stream);

  xg_kernel<<<T_, 256, 0, stream>>>(x, emb, W_ih, xg);
  lstm_kernel<<<256, 128, 0, stream>>>(W_hh, b_ih, b_hh, W_fc, b_fc, xg,
                                       flags, hbuf, hT, out);
}

// Round 5
// 1468.808 us; speedup vs baseline: 4.5746x; 1.6024x over previous
//
#include <hip/hip_runtime.h>
#include <hip/hip_bf16.h>

// Problem constants
#define B_  64
#define T_  512
#define E_  256
#define H_  512
#define G4_ 2048
#define C_  4

typedef __attribute__((ext_vector_type(4))) float  f32x4;
typedef __attribute__((ext_vector_type(8))) __bf16 bf16x8;
typedef __attribute__((ext_vector_type(8))) short  short8;   // no HIP builtin 'short8'
typedef __attribute__((ext_vector_type(4))) short  s16x4;    // HIP predefines 'short4'

union V16 { f32x4 f; bf16x8 b; short8 s; };

__device__ __forceinline__ float sigmoid_(float x) { return 1.0f / (1.0f + __expf(-x)); }
__device__ __forceinline__ float tanh_(float x)    { return 1.0f - 2.0f / (__expf(2.0f * x) + 1.0f); }

// Deterministic RNE fp32 -> bf16
__device__ __forceinline__ short f2bf(float f) {
  union { float f; unsigned u; } v; v.f = f;
  return (short)((v.u + 0x7FFFu + ((v.u >> 16) & 1u)) >> 16);
}

// --- per-access LLC-coherent ops (sc0 sc1 = bypass L1+L2, coherent point) ---
__device__ __forceinline__ void store_short_llc(void* p, unsigned v) {
  asm volatile("global_store_short %0, %1, off sc0 sc1" :: "v"(p), "v"(v) : "memory");
}
__device__ __forceinline__ void store_dword_llc(void* p, float v) {
  asm volatile("global_store_dword %0, %1, off sc0 sc1" :: "v"(p), "v"(v) : "memory");
}
// two pipelined coherent 16B loads + single drain
__device__ __forceinline__ void load2_dwordx4_llc(const void* p0, const void* p1,
                                                  f32x4* a, f32x4* b) {
  asm volatile(
      "global_load_dwordx4 %0, %2, off sc0 sc1\n\t"
      "global_load_dwordx4 %1, %3, off sc0 sc1\n\t"
      "s_waitcnt vmcnt(0)"
      : "=&v"(*a), "=&v"(*b) : "v"(p0), "v"(p1) : "memory");
}

// ---------------------------------------------------------------------------
// Phase 1: xg[t][g][b][d] — unchanged from round 3/4 (passed, ~170 us).
// ---------------------------------------------------------------------------
__global__ __launch_bounds__(256, 1) void xg_kernel(
    const int* __restrict__ x, const float* __restrict__ emb,
    const float* __restrict__ W_ih,
    __hip_bfloat16* __restrict__ xg)
{
  const int t   = blockIdx.x;
  const int tid = threadIdx.x;
  __shared__ int s_idx[B_];
  __shared__ __hip_bfloat16 s_e[B_][E_ + 8];

  if (tid < B_) s_idx[tid] = x[tid * T_ + t];
  __syncthreads();
  {
    int b = tid >> 2, ch = tid & 3;
    const float* src = emb + (size_t)s_idx[b] * E_ + ch * 64;
    short* dst = (short*)&s_e[b][ch * 64];
#pragma unroll
    for (int i = 0; i < 16; i++) {
      f32x4 v = *(const f32x4*)(src + i * 4);
      s16x4 s;
      s[0] = f2bf(v[0]); s[1] = f2bf(v[1]); s[2] = f2bf(v[2]); s[3] = f2bf(v[3]);
      *(s16x4*)(dst + i * 4) = s;
    }
  }
  __syncthreads();

  const int wv   = tid >> 6;
  const int lane = tid & 63;
  const int ln15 = lane & 15, quad = lane >> 4;

  V16 breg[4][8];
#pragma unroll
  for (int nt = 0; nt < 4; nt++)
#pragma unroll
    for (int ks = 0; ks < 8; ks++)
      breg[nt][ks].f = *(const f32x4*)(&s_e[nt * 16 + ln15][quad * 8 + ks * 32]);

  const int gbase = wv * 512;
  const size_t base_t = (size_t)t * (G4_ * B_);
  for (int mt = 0; mt < 32; mt++) {
    const int grow = gbase + mt * 16 + ln15;
    const float* arow = W_ih + (size_t)grow * E_ + quad * 8;
    V16 areg[8];
#pragma unroll
    for (int ks = 0; ks < 8; ks++) {
      f32x4 lo = *(const f32x4*)(arow + ks * 32);
      f32x4 hi = *(const f32x4*)(arow + ks * 32 + 4);
      short8 s;
      s[0] = f2bf(lo[0]); s[1] = f2bf(lo[1]); s[2] = f2bf(lo[2]); s[3] = f2bf(lo[3]);
      s[4] = f2bf(hi[0]); s[5] = f2bf(hi[1]); s[6] = f2bf(hi[2]); s[7] = f2bf(hi[3]);
      areg[ks].s = s;
    }

    f32x4 acc[4];
#pragma unroll
    for (int nt = 0; nt < 4; nt++) acc[nt] = (f32x4){0.f, 0.f, 0.f, 0.f};
#pragma unroll
    for (int ks = 0; ks < 8; ks++)
#pragma unroll
      for (int nt = 0; nt < 4; nt++)
        acc[nt] = __builtin_amdgcn_mfma_f32_16x16x32_bf16(areg[ks].b, breg[nt][ks].b, acc[nt], 0, 0, 0);

    const int mrow0 = gbase + mt * 16 + quad * 4;
#pragma unroll
    for (int nt = 0; nt < 4; nt++) {
      const int batch = nt * 16 + ln15;
#pragma unroll
      for (int r = 0; r < 4; r++) {
        const int grow2 = mrow0 + r;
        const int d = grow2 & 511;
        short sv = f2bf(acc[nt][r]);
        *((short*)xg + base_t + ((size_t)wv << 15) + ((size_t)batch << 9) + d) = sv;
      }
    }
  }
}

// ---------------------------------------------------------------------------
// Phase 2: persistent recurrent kernel, 64 blocks x 512 threads (8 waves).
// Block (pb = blk&3, pd = blk>>2): batches [pb*16,+16), h-dims [pd*32,+32)
// -> 128 gate rows. Sync domain = 16 blocks/batch group (was 64); 16 flags on
// ONE LLC line polled by 16 threads (was 64 flags / 128 threads). h_t staged
// once per block into LDS via coherent loads (16 KB/step), all 8 waves read
// fragments from LDS. W_hh bf16 fragments register-resident (64 VGPR).
// Per step: poll -> stage -> 16 MFMA/wave -> LDS scatter -> 1 gate cell/thread
// -> coherent h store -> barrier(vmcnt drain) -> flag publish.
// ---------------------------------------------------------------------------
__global__ __launch_bounds__(512, 2) void lstm_kernel(
    const float* __restrict__ W_hh,
    const float* __restrict__ b_ih, const float* __restrict__ b_hh,
    const float* __restrict__ W_fc, const float* __restrict__ b_fc,
    const __hip_bfloat16* __restrict__ xg,
    unsigned int* flags, __hip_bfloat16* hbuf /*[2][64][512]*/, float* hT,
    float* out)
{
  const int tid  = threadIdx.x;
  const int blk  = blockIdx.x;
  const int pb   = blk & 3;        // batch group
  const int pd   = blk >> 2;       // dim slice [pd*32, +32)
  const int d0   = pd * 32;
  const int wv   = tid >> 6;       // 0..7
  const int lane = tid & 63;
  const int ln15 = lane & 15, quad = lane >> 4;

  __shared__ __hip_bfloat16 s_h[16][520];      // h_t for our 16 batches (+8 pad)
  __shared__ float s_pre[4][16][36];           // [gate][batch][dim(+4 pad)]

  // Register-resident bf16 A fragments from fp32 W_hh.
  // Wave wv: gate g = wv>>1, local dims (wv&1)*16 + ln15.
  V16 areg[16];
  {
    const int grow = (wv >> 1) * 512 + d0 + (wv & 1) * 16 + ln15;
    const float* ap = W_hh + (size_t)grow * H_ + quad * 8;
#pragma unroll
    for (int ks = 0; ks < 16; ks++) {
      f32x4 lo = *(const f32x4*)(ap + ks * 32);
      f32x4 hi = *(const f32x4*)(ap + ks * 32 + 4);
      short8 s;
      s[0] = f2bf(lo[0]); s[1] = f2bf(lo[1]); s[2] = f2bf(lo[2]); s[3] = f2bf(lo[3]);
      s[4] = f2bf(hi[0]); s[5] = f2bf(hi[1]); s[6] = f2bf(hi[2]); s[7] = f2bf(hi[3]);
      areg[ks].s = s;
    }
  }

  // Gate-math mapping: exactly one cell per thread (16 batches x 32 dims = 512)
  const int nb = tid >> 5;         // 0..15
  const int nd = tid & 31;         // 0..31
  const int gb = pb * 16 + nb;     // global batch
  const int dg = d0 + nd;          // global h-dim
  const float bias_i = b_ih[dg]        + b_hh[dg];
  const float bias_f = b_ih[512 + dg]  + b_hh[512 + dg];
  const float bias_g = b_ih[1024 + dg] + b_hh[1024 + dg];
  const float bias_o = b_ih[1536 + dg] + b_hh[1536 + dg];
  float c = 0.0f;
  const int myflag = pb * 16 + pd;

  for (int t = 0; t < T_; t++) {
    const int cur = t & 1, nxt = cur ^ 1;

    // xg prefetch (plain cached loads; independent of h)
    const size_t xoff = (size_t)t * (G4_ * B_) + ((size_t)gb << 9) + dg;
    const __hip_bfloat16 xgi = xg[xoff];
    const __hip_bfloat16 xgf = xg[xoff + (1u << 15)];
    const __hip_bfloat16 xgg = xg[xoff + (2u << 15)];
    const __hip_bfloat16 xgo = xg[xoff + (3u << 15)];

    // Wait for all 16 producers of our batch group's h_t (flag >= t).
    if (tid < 16) {
      const unsigned* fp = flags + pb * 16 + tid;
      while (__hip_atomic_load(fp, __ATOMIC_RELAXED, __HIP_MEMORY_SCOPE_AGENT) < (unsigned)t) {}
    }
    __syncthreads();   // S1: h_t visible for everyone

    // Stage h_t -> LDS: 16 KB via 2 coherent 16B loads/thread, coalesced.
    {
      const short* hbase = (const short*)hbuf + (size_t)cur * (B_ * H_) + (size_t)(pb * 16) * H_;
      const int i0 = tid, i1 = tid + 512;      // i -> batch i>>6, chunk i&63
      f32x4 va, vb;
      load2_dwordx4_llc(hbase + i0 * 8, hbase + i1 * 8, &va, &vb);
      *(f32x4*)&s_h[i0 >> 6][(i0 & 63) * 8] = va;
      *(f32x4*)&s_h[i1 >> 6][(i1 & 63) * 8] = vb;
    }
    __syncthreads();   // S2: LDS staging complete

    // B fragments from LDS; 16 MFMAs on 2 accumulator chains.
    f32x4 acc0 = (f32x4){0.f, 0.f, 0.f, 0.f};
    f32x4 acc1 = (f32x4){0.f, 0.f, 0.f, 0.f};
#pragma unroll
    for (int ks = 0; ks < 16; ks += 2) {
      V16 b0, b1;
      b0.f = *(const f32x4*)&s_h[ln15][quad * 8 + ks * 32];
      b1.f = *(const f32x4*)&s_h[ln15][quad * 8 + (ks + 1) * 32];
      acc0 = __builtin_amdgcn_mfma_f32_16x16x32_bf16(areg[ks].b,     b0.b, acc0, 0, 0, 0);
      acc1 = __builtin_amdgcn_mfma_f32_16x16x32_bf16(areg[ks + 1].b, b1.b, acc1, 0, 0, 0);
    }
    const f32x4 accs = acc0 + acc1;

    // Scatter: C row m=quad*4+r -> d_local=(wv&1)*16+quad*4+r (consecutive in r)
    *(f32x4*)&s_pre[wv >> 1][ln15][(wv & 1) * 16 + quad * 4] = accs;
    __syncthreads();   // S3: preactivations complete

    {
      const float pi = s_pre[0][nb][nd] + bias_i + __bfloat162float(xgi);
      const float pf = s_pre[1][nb][nd] + bias_f + __bfloat162float(xgf);
      const float pg = s_pre[2][nb][nd] + bias_g + __bfloat162float(xgg);
      const float po = s_pre[3][nb][nd] + bias_o + __bfloat162float(xgo);
      const float i_ = sigmoid_(pi), f_ = sigmoid_(pf);
      const float g_ = tanh_(pg),    o_ = sigmoid_(po);
      c = f_ * c + i_ * g_;
      const float h = o_ * tanh_(c);
      if (t < T_ - 1) {
        short* hp = (short*)hbuf + (size_t)nxt * (B_ * H_) + (size_t)gb * H_ + dg;
        store_short_llc(hp, (unsigned)(unsigned short)f2bf(h));
      } else {
        store_dword_llc(hT + gb * H_ + dg, h);
      }
    }
    __syncthreads();   // S4: per-wave vmcnt(0) drain -> h stores acked at LLC

    if (tid == 0)
      __hip_atomic_store(&flags[myflag], (unsigned)(t + 1),
                         __ATOMIC_RELAXED, __HIP_MEMORY_SCOPE_AGENT);
  }

  // Phase 3: fp32 FC by block 0 (poll ALL 64 flags == T)
  if (blk == 0) {
    if (tid < 64)
      while (__hip_atomic_load(&flags[tid], __ATOMIC_RELAXED, __HIP_MEMORY_SCOPE_AGENT) < (unsigned)T_) {}
    __builtin_amdgcn_fence(__ATOMIC_ACQUIRE, "agent");
    __syncthreads();
    for (int o = tid; o < B_ * C_; o += 512) {
      const int b = o >> 2, cl = o & 3;
      const f32x4* hr = (const f32x4*)(hT + b * H_);
      const f32x4* wr = (const f32x4*)(W_fc + cl * H_);
      float s = 0.f;
      for (int d4 = 0; d4 < H_ / 4; d4++) {
        const f32x4 hv = hr[d4];
        const f32x4 wv4 = wr[d4];
        s += hv[0] * wv4[0] + hv[1] * wv4[1] + hv[2] * wv4[2] + hv[3] * wv4[3];
      }
      s += b_fc[cl];
      out[o] = s;
    }
  }
}

// ---------------------------------------------------------------------------
// Workspace map:
//   [0, 1024)            : flags[256] (uint32; group g at words [g*16,g*16+16))
//   [4096, 135168)       : hbuf[2][64][512] bf16 (both buffers zeroed = h0)
//   [135168, 266240)     : hT[64][512] fp32
//   [524288, 134742016)  : xg[T][4][B][512] bf16 (128 MiB)
// ---------------------------------------------------------------------------
extern "C" void kernel_launch(void* const* d_in, const int* in_sizes, int n_in,
                              void* d_out, int out_size, void* d_ws, size_t ws_size,
                              hipStream_t stream) {
  const int*   x    = (const int*)d_in[0];
  const float* emb  = (const float*)d_in[1];
  const float* W_ih = (const float*)d_in[2];
  const float* W_hh = (const float*)d_in[3];
  const float* b_ih = (const float*)d_in[4];
  const float* b_hh = (const float*)d_in[5];
  const float* W_fc = (const float*)d_in[6];
  const float* b_fc = (const float*)d_in[7];
  float* out = (float*)d_out;

  char* ws = (char*)d_ws;
  const size_t XG_OFF = 524288;
  const size_t NEEDED = XG_OFF + (size_t)T_ * G4_ * B_ * 2;
  if (ws_size < NEEDED) return;

  unsigned int*   flags = (unsigned int*)ws;
  __hip_bfloat16* hbuf  = (__hip_bfloat16*)(ws + 4096);
  float*          hT    = (float*)(ws + 135168);
  __hip_bfloat16* xg    = (__hip_bfloat16*)(ws + XG_OFF);

  (void)hipMemsetAsync(ws, 0, 135168, stream);

  xg_kernel<<<T_, 256, 0, stream>>>(x, emb, W_ih, xg);
  lstm_kernel<<<64, 512, 0, stream>>>(W_hh, b_ih, b_hh, W_fc, b_fc, xg,
                                      flags, hbuf, hT, out);
}